// Round 4
// baseline (1219.573 us; speedup 1.0000x reference)
//
#include <hip/hip_runtime.h>
#include <math.h>

#define NNODES 100000
#define NEDGES 200000
#define HD 64
#define NP2 250000
#define NP3 500000
#define NG 2048
#define NCLS 10
#define NFEAT 18
#define EFEAT 18

typedef short short8v __attribute__((ext_vector_type(8)));
typedef float f32x4 __attribute__((ext_vector_type(4)));
typedef float f32x2 __attribute__((ext_vector_type(2)));

#ifndef __has_builtin
#define __has_builtin(x) 0
#endif
#if __has_builtin(__builtin_amdgcn_global_atomic_fadd_v2f32)
#define USE_PK_ATOMIC 1
#endif

__device__ __forceinline__ float fsig(float x) { return 1.0f / (1.0f + __expf(-x)); }
__device__ __forceinline__ float ftanh(float x) {
    float t = __expf(-2.0f * fabsf(x));
    float r = (1.0f - t) / (1.0f + t);
    return x < 0.f ? -r : r;
}

// pack two f32 -> bf16 pair (RNE), a in low 16, b in high 16
__device__ __forceinline__ unsigned bfpack(float a, float b) {
    unsigned ua = __builtin_bit_cast(unsigned, a);
    unsigned ub = __builtin_bit_cast(unsigned, b);
    ua = (ua + 0x7FFFu + ((ua >> 16) & 1u)) >> 16;
    ub = (ub + 0x7FFFu + ((ub >> 16) & 1u)) & 0xFFFF0000u;
    return ua | ub;
}
__device__ __forceinline__ unsigned short bf16r(float a) {
    unsigned u = __builtin_bit_cast(unsigned, a);
    return (unsigned short)((u + 0x7FFFu + ((u >> 16) & 1u)) >> 16);
}

// 8-byte packed atomic add (2 consecutive floats); addr must be 8B-aligned
__device__ __forceinline__ void atomic_fadd2(float* addr, float a, float b) {
#ifdef USE_PK_ATOMIC
    f32x2 d; d[0] = a; d[1] = b;
    __builtin_amdgcn_global_atomic_fadd_v2f32(
        (__attribute__((address_space(1))) f32x2*)addr, d);
#else
    atomicAdd(addr, a);
    atomicAdd(addr + 1, b);
#endif
}

// ---------------------------------------------------------------------------
// bsum[j] = b_ih[j] + b_hh[j]
// ---------------------------------------------------------------------------
__global__ void prep_bias(const float* __restrict__ b_ih, const float* __restrict__ b_hh,
                          float* __restrict__ bsum) {
    int j = threadIdx.x;
    bsum[j] = b_ih[j] + b_hh[j];
}

// ---------------------------------------------------------------------------
// Bp: bf16 B image, 6 chunks x [256 n' x 40 shorts] (32 data + 8 pad).
// Column permutation: n' = nt*16 + cc, nt = q*4 + j  ->  original column
// n = q*64 + h, h = 2*cc + (j&1) + 32*(j>>1).  This makes lane cc own
// hidden {2cc, 2cc+1, 2cc+32, 2cc+33} -> packed-pair atomics in the conv.
// B[k][n] = k<128 ? w_ih[n][k] : w_hh[n][k-128].
// ---------------------------------------------------------------------------
__global__ void prep_bp(const float* __restrict__ w_ih, const float* __restrict__ w_hh,
                        unsigned short* __restrict__ Bp) {
    int gid = blockIdx.x * 256 + threadIdx.x;
    if (gid >= 6 * 256 * 40) return;
    int kc = gid / 10240;
    int rem = gid - kc * 10240;
    int np = rem / 40, kk = rem - np * 40;
    unsigned short v = 0;
    if (kk < 32) {
        int k = kc * 32 + kk;
        int nt = np >> 4, cc = np & 15;
        int j = nt & 3, qg = nt >> 2;
        int h = 2 * cc + (j & 1) + 32 * (j >> 1);
        int n = qg * 64 + h;
        float f = (k < 128) ? w_ih[n * 128 + k] : w_hh[n * 64 + (k - 128)];
        v = bf16r(f);
    }
    Bp[gid] = v;
}

// ---------------------------------------------------------------------------
// Feature encoders
// ---------------------------------------------------------------------------
__global__ void encode_both(const float* __restrict__ X, const float* __restrict__ Wf,
                            const float* __restrict__ bf, float* __restrict__ out,
                            unsigned short* __restrict__ outb, long n, int F) {
    long gid = (long)blockIdx.x * 256 + threadIdx.x;
    if (gid >= n * 64) return;
    long r = gid >> 6;
    int col = (int)(gid & 63);
    float acc = bf[col];
    const float* xr = X + r * F;
    for (int k = 0; k < F; ++k) acc += xr[k] * Wf[k * 64 + col];
    out[gid] = acc;
    outb[gid] = bf16r(acc);
}

__global__ void encode_bf(const float* __restrict__ X, const float* __restrict__ Wf,
                          const float* __restrict__ bf, unsigned short* __restrict__ outb,
                          long n, int F) {
    long gid = (long)blockIdx.x * 256 + threadIdx.x;
    if (gid >= n * 64) return;
    long r = gid >> 6;
    int col = (int)(gid & 63);
    float acc = bf[col];
    const float* xr = X + r * F;
    for (int k = 0; k < F; ++k) acc += xr[k] * Wf[k * 64 + col];
    outb[gid] = bf16r(acc);
}

// ---------------------------------------------------------------------------
// MFMA LSTM path conv. Block = 256 threads (4 waves) handles 64 paths.
// Inputs xb/eab are bf16 rows (128B) -> gather is straight uint4 copies.
// Al (LDS, bf16): [p=64][k], stride 200 shorts; k 0..63 node, 64..127 edge,
// 128..191 h.  Bg: streamed B chunk [n'=256][kk=32], stride 40 shorts.
// mfma_f32_16x16x32_bf16, C layout col=lane&15, row=(lane>>4)*4+reg.
// With the Bp column permutation, lane (c=lane&15,q=lane>>4), acc tile
// nt=qg*4+j reg r = gate qg of hidden h(j,c)={2c,2c+1,2c+32,2c+33}, path
// w*16+q*4+r.  Activation in registers; final scatter = 2 packed atomics.
// Step 0 skips chunks 2..5 (edge=0, h=0).
// ---------------------------------------------------------------------------
template <int L>
__global__ __launch_bounds__(256, 3)
void conv_mfma(const unsigned short* __restrict__ xb, const unsigned short* __restrict__ eab,
               const int* __restrict__ paths, const int* __restrict__ ei,
               const unsigned short* __restrict__ Bp, const float* __restrict__ bsum,
               float* __restrict__ hsum, int P) {
    __shared__ unsigned short Al[64 * 200];
    __shared__ unsigned short Bg[256 * 40];

    const int t = threadIdx.x;
    const int w = t >> 6, lane = t & 63;
    const int c = lane & 15, q = lane >> 4;
    const int pl = t >> 2, gq = t & 3;          // gather: path-local, row quarter
    const long pg = (long)blockIdx.x * 64 + pl;
    const int pc = (pg < P) ? (int)pg : P - 1;

    float breg[16];
#pragma unroll
    for (int nt = 0; nt < 16; ++nt) {
        int j = nt & 3;
        int h = 2 * c + (j & 1) + 32 * (j >> 1);
        breg[nt] = bsum[(nt >> 2) * 64 + h];
    }
    float creg[16];
#pragma unroll
    for (int i = 0; i < 16; ++i) creg[i] = 0.f;

    f32x4 acc[16];

    for (int step = 0; step < L; ++step) {
        // ---- gather bf16 rows -> Al (node 0..63, edge 64..127)
        {
            int node = paths[pc * L + step];
            const uint4* s4 = (const uint4*)(xb + (size_t)node * HD);
            uint4 u0 = s4[2 * gq], u1 = s4[2 * gq + 1];
            *(uint4*)&Al[pl * 200 + gq * 16] = u0;
            *(uint4*)&Al[pl * 200 + gq * 16 + 8] = u1;
            if (step > 0) {
                int e = ei[pc * (L - 1) + (step - 1)];
                const uint4* e4 = (const uint4*)(eab + (size_t)e * HD);
                uint4 v0 = e4[2 * gq], v1 = e4[2 * gq + 1];
                *(uint4*)&Al[pl * 200 + 64 + gq * 16] = v0;
                *(uint4*)&Al[pl * 200 + 64 + gq * 16 + 8] = v1;
            }
        }
        // ---- init accumulators with bias
#pragma unroll
        for (int nt = 0; nt < 16; ++nt) {
            f32x4 v; v[0] = breg[nt]; v[1] = breg[nt]; v[2] = breg[nt]; v[3] = breg[nt];
            acc[nt] = v;
        }
        // ---- MFMA GEMM over K chunks (step 0: only x-part, chunks 0..1)
        const int kc_end = (step == 0) ? 2 : 6;
        for (int kc = 0; kc < kc_end; ++kc) {
            __syncthreads();   // gather/h writes visible; prev Bg readers done
            {
                const float4* src = (const float4*)(Bp + kc * 10240);
                float4* dst = (float4*)Bg;
#pragma unroll
                for (int j = 0; j < 5; ++j) dst[t + j * 256] = src[t + j * 256];
            }
            __syncthreads();
            short8v af = *(const short8v*)&Al[(w * 16 + c) * 200 + kc * 32 + q * 8];
#pragma unroll
            for (int nt = 0; nt < 16; ++nt) {
                short8v bf = *(const short8v*)&Bg[(nt * 16 + c) * 40 + q * 8];
                acc[nt] = __builtin_amdgcn_mfma_f32_16x16x32_bf16(af, bf, acc[nt], 0, 0, 0);
            }
        }
        __syncthreads();       // all frag reads done before h-writeback
        // ---- activation (registers); (r,j): path w*16+q*4+r, hidden h(j,c)
#pragma unroll
        for (int r = 0; r < 4; ++r) {
            float hv[4];
#pragma unroll
            for (int j = 0; j < 4; ++j) {
                float gi = acc[j][r], gf = acc[4 + j][r];
                float gg = acc[8 + j][r], go = acc[12 + j][r];
                float cn = fsig(gf) * creg[j * 4 + r] + fsig(gi) * ftanh(gg);
                creg[j * 4 + r] = cn;
                hv[j] = fsig(go) * ftanh(cn);
            }
            if (step < L - 1) {
                int p = w * 16 + q * 4 + r;
                *(unsigned*)&Al[p * 200 + 128 + 2 * c] = bfpack(hv[0], hv[1]);
                *(unsigned*)&Al[p * 200 + 160 + 2 * c] = bfpack(hv[2], hv[3]);
            } else {
                long pr = (long)blockIdx.x * 64 + w * 16 + q * 4 + r;
                if (pr < P) {
                    int node = paths[pr * L + (L - 1)];
                    float* bp2 = hsum + (size_t)node * HD + 2 * c;
                    atomic_fadd2(bp2, hv[0], hv[1]);
                    atomic_fadd2(bp2 + 32, hv[2], hv[3]);
                }
            }
        }
    }
}

// ---------------------------------------------------------------------------
// Per-column sum / sumsq over rows (for BN stats)
// ---------------------------------------------------------------------------
__global__ void col_stats(const float* __restrict__ X, int nrows, float* __restrict__ out) {
    int col = threadIdx.x & 63, rg = threadIdx.x >> 6;
    float s = 0.f, q = 0.f;
    long stride = (long)gridDim.x * 4;
    for (long r = (long)blockIdx.x * 4 + rg; r < nrows; r += stride) {
        float v = X[r * 64 + col];
        s += v;
        q += v * v;
    }
    __shared__ float red[2][256];
    red[0][threadIdx.x] = s;
    red[1][threadIdx.x] = q;
    __syncthreads();
    if (threadIdx.x < 64) {
        int c = threadIdx.x;
        float ss = red[0][c] + red[0][c + 64] + red[0][c + 128] + red[0][c + 192];
        float qq = red[1][c] + red[1][c + 64] + red[1][c + 128] + red[1][c + 192];
        atomicAdd(out + c, ss);
        atomicAdd(out + 64 + c, qq);
    }
}

// stats -> per-column affine: y = x*a + c  implements BN(g,b)
__global__ void bn_finalize(const float* __restrict__ stats, const float* __restrict__ g,
                            const float* __restrict__ b, int nrows, float* __restrict__ ab) {
    int h = threadIdx.x;
    if (h >= 64) return;
    float inv = 1.0f / (float)nrows;
    float mean = stats[h] * inv;
    float var = stats[64 + h] * inv - mean * mean;
    float a = g[h] * rsqrtf(var + 1e-5f);
    ab[h] = a;
    ab[64 + h] = b[h] - mean * a;
}

// ---------------------------------------------------------------------------
// Y[n][j] = sum_k inAct(X[n][k]*a[k]+c[k]) * W[k][j] + bias[j]
// optional fused column stats of Y
// ---------------------------------------------------------------------------
template <bool INRELU, bool STATS>
__global__ __launch_bounds__(256)
void gemm64(const float* __restrict__ X, const float* __restrict__ ab,
            const float* __restrict__ W, const float* __restrict__ bias,
            float* __restrict__ Y, float* stats, int nrows) {
    __shared__ float Xs[64 * 64];
    __shared__ float red[2][256];
    const int t = threadIdx.x;
    const int col = t & 63, rg = t >> 6;
    const long r0 = (long)blockIdx.x * 64;

    float a = 1.f, c = 0.f;
    if (ab) { a = ab[col]; c = ab[64 + col]; }

    for (int i = 0; i < 16; ++i) {
        int rl = rg * 16 + i;
        long r = r0 + rl;
        float v = (r < nrows) ? X[r * 64 + col] : 0.f;
        v = v * a + c;
        if (INRELU) v = fmaxf(v, 0.f);
        Xs[rl * 64 + col] = v;
    }
    __syncthreads();

    float wreg[64];
#pragma unroll
    for (int k = 0; k < 64; ++k) wreg[k] = W[k * 64 + col];
    float bs = bias[col];
    float ssum = 0.f, ssq = 0.f;

    for (int i = 0; i < 16; ++i) {
        int rl = rg * 16 + i;
        long r = r0 + rl;
        const float4* xs4 = (const float4*)(Xs + rl * 64);
        float acc = bs;
#pragma unroll
        for (int k4 = 0; k4 < 16; ++k4) {
            float4 xv = xs4[k4];
            acc += xv.x * wreg[4 * k4] + xv.y * wreg[4 * k4 + 1] +
                   xv.z * wreg[4 * k4 + 2] + xv.w * wreg[4 * k4 + 3];
        }
        if (r < nrows) {
            Y[r * 64 + col] = acc;
            ssum += acc;
            ssq += acc * acc;
        }
    }
    if (STATS) {
        red[0][t] = ssum;
        red[1][t] = ssq;
        __syncthreads();
        if (t < 64) {
            float s = red[0][t] + red[0][t + 64] + red[0][t + 128] + red[0][t + 192];
            float qq = red[1][t] + red[1][t + 64] + red[1][t + 128] + red[1][t + 192];
            atomicAdd(stats + t, s);
            atomicAdd(stats + 64 + t, qq);
        }
    }
}

// conv1 epilogue: W1 = relu(W1*a+c); Winb = bf16(0.75*W0 - 0.25*W1)
__global__ void bn_apply1(float* __restrict__ W1, const float* __restrict__ ab,
                          const float* __restrict__ W0, unsigned short* __restrict__ Winb,
                          long n) {
    long gid = (long)blockIdx.x * 256 + threadIdx.x;
    if (gid >= n * 64) return;
    int col = (int)(gid & 63);
    float v = fmaxf(W1[gid] * ab[col] + ab[64 + col], 0.f);
    W1[gid] = v;
    Winb[gid] = bf16r(0.75f * W0[gid] - 0.25f * v);
}

// conv2 epilogue fused with attention dots:
// W2 = relu(W2*a+c); atts[h] += sum W0*W1; atts[64+h] += sum W0*W2
__global__ void bn_apply_att(float* __restrict__ W2, const float* __restrict__ ab,
                             const float* __restrict__ W0, const float* __restrict__ W1,
                             float* __restrict__ atts, int n) {
    int col = threadIdx.x & 63, rg = threadIdx.x >> 6;
    float a = ab[col], c = ab[64 + col];
    float s1 = 0.f, s2 = 0.f;
    long stride = (long)gridDim.x * 4;
    for (long r = (long)blockIdx.x * 4 + rg; r < n; r += stride) {
        long gid = r * 64 + col;
        float v = fmaxf(W2[gid] * a + c, 0.f);
        W2[gid] = v;
        float q0 = W0[gid];
        s1 += q0 * W1[gid];
        s2 += q0 * v;
    }
    __shared__ float red[2][256];
    red[0][threadIdx.x] = s1;
    red[1][threadIdx.x] = s2;
    __syncthreads();
    if (threadIdx.x < 64) {
        int cc = threadIdx.x;
        float a1 = red[0][cc] + red[0][cc + 64] + red[0][cc + 128] + red[0][cc + 192];
        float a2 = red[1][cc] + red[1][cc + 64] + red[1][cc + 128] + red[1][cc + 192];
        atomicAdd(atts + cc, a1);
        atomicAdd(atts + 64 + cc, a2);
    }
}

// single wave: normalize scores, dot w_att, softmax over the 2 -> watt[0..1]
__global__ void att_softmax(const float* __restrict__ atts, const float* __restrict__ w_att,
                            const float* __restrict__ b_att, float* __restrict__ watt) {
    int h = threadIdx.x;  // 0..63
    float z[2];
    for (int k = 0; k < 2; ++k) {
        float s = atts[64 * k + h];
        float mn = s, mx = s;
        for (int off = 32; off > 0; off >>= 1) {
            mn = fminf(mn, __shfl_down(mn, off));
            mx = fmaxf(mx, __shfl_down(mx, off));
        }
        mn = __shfl(mn, 0);
        mx = __shfl(mx, 0);
        float sn = (s - mn) / (mx - mn + 1e-6f);
        float d = sn * w_att[h];
        for (int off = 32; off > 0; off >>= 1) d += __shfl_down(d, off);
        z[k] = __shfl(d, 0) + b_att[0];
    }
    if (h == 0) {
        float m = fmaxf(z[0], z[1]);
        float e0 = expf(z[0] - m), e1 = expf(z[1] - m);
        float inv = 1.0f / (e0 + e1);
        watt[0] = e0 * inv;
        watt[1] = e1 * inv;
    }
}

// rep = W0 + w1*W1 + w2*W2, scatter-add into pooled[batch[n]]
__global__ void pool_rep(const float* __restrict__ W0, const float* __restrict__ W1,
                         const float* __restrict__ W2, const float* __restrict__ watt,
                         const int* __restrict__ batch, float* __restrict__ pooled, int n) {
    long gid = (long)blockIdx.x * 256 + threadIdx.x;
    if (gid >= (long)n * 64) return;
    long r = gid >> 6;
    int col = (int)(gid & 63);
    float w1 = watt[0], w2 = watt[1];
    float rep = W0[gid] + w1 * W1[gid] + w2 * W2[gid];
    atomicAdd(pooled + (size_t)batch[r] * 64 + col, rep);
}

// out[g][j] = sum_k relu(X[g][k]) * W[k][j] + b[j]   (W is 64 x 10)
__global__ void lin2_kernel(const float* __restrict__ X, const float* __restrict__ W,
                            const float* __restrict__ b, float* __restrict__ out, int g_count) {
    int gid = blockIdx.x * 256 + threadIdx.x;
    if (gid >= g_count * NCLS) return;
    int g = gid / NCLS, j = gid - g * NCLS;
    float acc = b[j];
    const float* xr = X + (size_t)g * 64;
    for (int k = 0; k < 64; ++k) acc += fmaxf(xr[k], 0.f) * W[k * NCLS + j];
    out[gid] = acc;
}

// ---------------------------------------------------------------------------
extern "C" void kernel_launch(void* const* d_in, const int* in_sizes, int n_in,
                              void* d_out, int out_size, void* d_ws, size_t ws_size,
                              hipStream_t stream) {
    const float* x         = (const float*)d_in[0];
    const float* edge_attr = (const float*)d_in[1];
    const int*   paths2    = (const int*)d_in[2];
    const int*   ei2       = (const int*)d_in[3];
    const int*   paths3    = (const int*)d_in[4];
    const int*   ei3       = (const int*)d_in[5];
    const int*   batch     = (const int*)d_in[6];
    const float* w_feat    = (const float*)d_in[7];
    const float* b_feat    = (const float*)d_in[8];
    const float* w_bond    = (const float*)d_in[9];
    const float* b_bond    = (const float*)d_in[10];
    const float* w_ih      = (const float*)d_in[11];
    const float* w_hh      = (const float*)d_in[12];
    const float* b_ih      = (const float*)d_in[13];
    const float* b_hh      = (const float*)d_in[14];
    const float* bn_g      = (const float*)d_in[15];
    const float* bn_b      = (const float*)d_in[16];
    const float* mlp_w1    = (const float*)d_in[17];
    const float* mlp_b1    = (const float*)d_in[18];
    const float* bn1_g     = (const float*)d_in[19];
    const float* bn1_b     = (const float*)d_in[20];
    const float* mlp_w2    = (const float*)d_in[21];
    const float* mlp_b2    = (const float*)d_in[22];
    const float* bn2_g     = (const float*)d_in[23];
    const float* bn2_b     = (const float*)d_in[24];
    const float* w_att     = (const float*)d_in[25];
    const float* b_att     = (const float*)d_in[26];
    const float* w_l1      = (const float*)d_in[27];
    const float* b_l1      = (const float*)d_in[28];
    const float* w_l2      = (const float*)d_in[29];
    const float* b_l2      = (const float*)d_in[30];

    const size_t N64 = (size_t)NNODES * 64;
    float* ws = (float*)d_ws;
    float* W0     = ws;                               // N*64 f32
    float* W1     = W0 + N64;                         // N*64 f32
    float* W2     = W1 + N64;                         // N*64 f32
    float* Wtmp   = W2 + N64;                         // N*64 f32
    float* hsum   = Wtmp + N64;                       // N*64 f32
    unsigned short* W0b  = (unsigned short*)(hsum + N64);   // N*64 bf16
    unsigned short* Winb = W0b + N64;                       // N*64 bf16
    unsigned short* eab  = Winb + N64;                      // E*64 bf16
    unsigned short* Bp   = eab + (size_t)NEDGES * 64;       // 6*256*40 bf16
    float* bsum   = (float*)(Bp + 6 * 256 * 40);      // 256
    float* st     = bsum + 256;                       // 6*128
    float* abuf   = st + 6 * 128;                     // 6*128
    float* atts   = abuf + 6 * 128;                   // 128
    float* watt   = atts + 128;                       // 64 (2 used)
    float* pooled = watt + 64;                        // G*64
    float* lin1   = pooled + (size_t)NG * 64;         // G*64

    // zero: stats region (st..watt inclusive), pooled, hsum
    hipMemsetAsync(st, 0, (6 * 128 + 6 * 128 + 128 + 64) * sizeof(float), stream);
    hipMemsetAsync(pooled, 0, (size_t)NG * 64 * sizeof(float), stream);
    hipMemsetAsync(hsum, 0, N64 * sizeof(float), stream);

    prep_bias<<<1, 256, 0, stream>>>(b_ih, b_hh, bsum);
    prep_bp<<<240, 256, 0, stream>>>(w_ih, w_hh, Bp);
    encode_both<<<(NNODES * 64 + 255) / 256, 256, 0, stream>>>(x, w_feat, b_feat, W0, W0b, NNODES, NFEAT);
    encode_bf<<<(NEDGES * 64 + 255) / 256, 256, 0, stream>>>(edge_attr, w_bond, b_bond, eab, NEDGES, EFEAT);

    // ---------------- conv 1 (L=2) ----------------
    conv_mfma<2><<<(NP2 + 63) / 64, 256, 0, stream>>>(W0b, eab, paths2, ei2, Bp, bsum, hsum, NP2);

    col_stats<<<256, 256, 0, stream>>>(hsum, NNODES, st + 0);
    bn_finalize<<<1, 64, 0, stream>>>(st + 0, bn_g + 0, bn_b + 0, NNODES, abuf + 0);
    gemm64<false, true><<<(NNODES + 63) / 64, 256, 0, stream>>>(hsum, abuf + 0, mlp_w1, mlp_b1, Wtmp, st + 128, NNODES);
    bn_finalize<<<1, 64, 0, stream>>>(st + 128, bn1_g + 0, bn1_b + 0, NNODES, abuf + 128);
    gemm64<true, true><<<(NNODES + 63) / 64, 256, 0, stream>>>(Wtmp, abuf + 128, mlp_w2, mlp_b2, W1, st + 256, NNODES);
    bn_finalize<<<1, 64, 0, stream>>>(st + 256, bn2_g + 0, bn2_b + 0, NNODES, abuf + 256);
    bn_apply1<<<(NNODES * 64 + 255) / 256, 256, 0, stream>>>(W1, abuf + 256, W0, Winb, NNODES);

    // ---------------- conv 2 (L=3) ----------------
    hipMemsetAsync(hsum, 0, N64 * sizeof(float), stream);
    conv_mfma<3><<<(NP3 + 63) / 64, 256, 0, stream>>>(Winb, eab, paths3, ei3, Bp, bsum, hsum, NP3);

    col_stats<<<256, 256, 0, stream>>>(hsum, NNODES, st + 384);
    bn_finalize<<<1, 64, 0, stream>>>(st + 384, bn_g + 64, bn_b + 64, NNODES, abuf + 384);
    gemm64<false, true><<<(NNODES + 63) / 64, 256, 0, stream>>>(hsum, abuf + 384, mlp_w1 + 4096, mlp_b1 + 64, Wtmp, st + 512, NNODES);
    bn_finalize<<<1, 64, 0, stream>>>(st + 512, bn1_g + 64, bn1_b + 64, NNODES, abuf + 512);
    gemm64<true, true><<<(NNODES + 63) / 64, 256, 0, stream>>>(Wtmp, abuf + 512, mlp_w2 + 4096, mlp_b2 + 64, W2, st + 640, NNODES);
    bn_finalize<<<1, 64, 0, stream>>>(st + 640, bn2_g + 64, bn2_b + 64, NNODES, abuf + 640);
    bn_apply_att<<<256, 256, 0, stream>>>(W2, abuf + 640, W0, W1, atts, NNODES);

    // ---------------- attention + pooling + head ----------------
    att_softmax<<<1, 64, 0, stream>>>(atts, w_att, b_att, watt);
    pool_rep<<<(NNODES * 64 + 255) / 256, 256, 0, stream>>>(W0, W1, W2, watt, batch, pooled, NNODES);
    gemm64<false, false><<<NG / 64, 256, 0, stream>>>(pooled, nullptr, w_l1, b_l1, lin1, nullptr, NG);
    lin2_kernel<<<(NG * NCLS + 255) / 256, 256, 0, stream>>>(lin1, w_l2, b_l2, (float*)d_out, NG);
}

// Round 5
// 985.426 us; speedup vs baseline: 1.2376x; 1.2376x over previous
//
#include <hip/hip_runtime.h>
#include <math.h>

#define NNODES 100000
#define NEDGES 200000
#define HD 64
#define NP2 250000
#define NP3 500000
#define NG 2048
#define NCLS 10
#define NFEAT 18
#define EFEAT 18

typedef short short8v __attribute__((ext_vector_type(8)));
typedef float f32x4 __attribute__((ext_vector_type(4)));

__device__ __forceinline__ unsigned short bf16r(float a) {
    unsigned u = __builtin_bit_cast(unsigned, a);
    return (unsigned short)((u + 0x7FFFu + ((u >> 16) & 1u)) >> 16);
}

// ---------------------------------------------------------------------------
// bsum[j] = b_ih[j] + b_hh[j]
// ---------------------------------------------------------------------------
__global__ void prep_bias(const float* __restrict__ b_ih, const float* __restrict__ b_hh,
                          float* __restrict__ bsum) {
    int j = threadIdx.x;
    bsum[j] = b_ih[j] + b_hh[j];
}

// ---------------------------------------------------------------------------
// Bp: bf16 B image as MFMA fragment blobs.
// Bp[((kc*16 + nt)*64 + l)*8 + j] = bf16(B[k][n]),
//   k = kc*32 + (l>>4)*8 + j,  nt = jh*4 + qg,  n = qg*64 + 16*jh + (l&15).
//   B[k][n] = k<128 ? w_ih[n][k] : w_hh[n][k-128].
// Wave w of the conv owns jh=w -> hidden [16w,16w+16) x 4 gates, with its 24
// fragments (6 kc x 4 qg) register-resident; lane reads are 16B coalesced.
// ---------------------------------------------------------------------------
__global__ void prep_bp(const float* __restrict__ w_ih, const float* __restrict__ w_hh,
                        unsigned short* __restrict__ Bp) {
    int gid = blockIdx.x * 256 + threadIdx.x;
    if (gid >= 6 * 16 * 64 * 8) return;
    int kc = gid >> 13;
    int rem = gid & 8191;
    int nt = rem >> 9;
    int rem2 = rem & 511;
    int l = rem2 >> 3, j = rem2 & 7;
    int c = l & 15, q = l >> 4;
    int jh = nt >> 2, qg = nt & 3;
    int k = kc * 32 + q * 8 + j;
    int n = qg * 64 + 16 * jh + c;
    float f = (k < 128) ? w_ih[n * 128 + k] : w_hh[n * 64 + (k - 128)];
    Bp[gid] = bf16r(f);
}

// ---------------------------------------------------------------------------
// Feature encoders
// ---------------------------------------------------------------------------
__global__ void encode_both(const float* __restrict__ X, const float* __restrict__ Wf,
                            const float* __restrict__ bf, float* __restrict__ out,
                            unsigned short* __restrict__ outb, long n, int F) {
    long gid = (long)blockIdx.x * 256 + threadIdx.x;
    if (gid >= n * 64) return;
    long r = gid >> 6;
    int col = (int)(gid & 63);
    float acc = bf[col];
    const float* xr = X + r * F;
    for (int k = 0; k < F; ++k) acc += xr[k] * Wf[k * 64 + col];
    out[gid] = acc;
    outb[gid] = bf16r(acc);
}

__global__ void encode_bf(const float* __restrict__ X, const float* __restrict__ Wf,
                          const float* __restrict__ bf, unsigned short* __restrict__ outb,
                          long n, int F) {
    long gid = (long)blockIdx.x * 256 + threadIdx.x;
    if (gid >= n * 64) return;
    long r = gid >> 6;
    int col = (int)(gid & 63);
    float acc = bf[col];
    const float* xr = X + r * F;
    for (int k = 0; k < F; ++k) acc += xr[k] * Wf[k * 64 + col];
    outb[gid] = bf16r(acc);
}

// ---------------------------------------------------------------------------
// MFMA LSTM path conv, register-resident B.
// Block = 256 threads (4 waves) x 64 paths.  Al (LDS, bf16): [p=64][k],
// stride 200 shorts; k 0..63 node, 64..127 edge, 128..191 h(prev step).
// Wave w: acc[mt][qg] (mt = path quarter, qg = gate) over hidden [16w,16w+16).
// Lane (c,q) reg r: path mt*16+q*4+r, hidden 16w+c.  Per step: 2 barriers,
// 24 ds_read_b128, 96 MFMA, zero global staging.  Step 0: chunks 0..1 only
// (edge=0, h=0 contribute nothing).  Activation in registers, 7 transcendental
// (5 v_exp + 2 v_rcp) per cell via common-denominator form.
// ---------------------------------------------------------------------------
template <int L>
__global__ __launch_bounds__(256, 2)
void conv_mfma(const unsigned short* __restrict__ xb, const unsigned short* __restrict__ eab,
               const int* __restrict__ paths, const int* __restrict__ ei,
               const unsigned short* __restrict__ Bp, const float* __restrict__ bsum,
               float* __restrict__ hsum, int P) {
    __shared__ unsigned short Al[64 * 200];

    const int t = threadIdx.x;
    const int w = t >> 6, lane = t & 63;
    const int c = lane & 15, q = lane >> 4;
    const int pl = t >> 2, gq = t & 3;          // gather: path-local, row quarter
    const long pg = (long)blockIdx.x * 64 + pl;
    const int pc = (pg < P) ? (int)pg : P - 1;

    // ---- B fragments: register-resident for the whole kernel
    short8v Bfr[6][4];
#pragma unroll
    for (int kc = 0; kc < 6; ++kc)
#pragma unroll
        for (int qg = 0; qg < 4; ++qg)
            Bfr[kc][qg] = *(const short8v*)&Bp[(((kc * 16) + (w * 4 + qg)) * 64 + lane) * 8];

    float breg[4];
#pragma unroll
    for (int qg = 0; qg < 4; ++qg) breg[qg] = bsum[qg * 64 + 16 * w + c];

    float creg[16];
#pragma unroll
    for (int i = 0; i < 16; ++i) creg[i] = 0.f;

    f32x4 acc[4][4];

    for (int step = 0; step < L; ++step) {
        // ---- gather bf16 rows -> Al (node 0..63, edge 64..127)
        {
            int node = paths[pc * L + step];
            const uint4* s4 = (const uint4*)(xb + (size_t)node * HD);
            uint4 u0 = s4[2 * gq], u1 = s4[2 * gq + 1];
            *(uint4*)&Al[pl * 200 + gq * 16] = u0;
            *(uint4*)&Al[pl * 200 + gq * 16 + 8] = u1;
            if (step > 0) {
                int e = ei[pc * (L - 1) + (step - 1)];
                const uint4* e4 = (const uint4*)(eab + (size_t)e * HD);
                uint4 v0 = e4[2 * gq], v1 = e4[2 * gq + 1];
                *(uint4*)&Al[pl * 200 + 64 + gq * 16] = v0;
                *(uint4*)&Al[pl * 200 + 64 + gq * 16 + 8] = v1;
            }
        }
        // ---- init accumulators with bias
#pragma unroll
        for (int mt = 0; mt < 4; ++mt)
#pragma unroll
            for (int qg = 0; qg < 4; ++qg) {
                f32x4 v; v[0] = breg[qg]; v[1] = breg[qg]; v[2] = breg[qg]; v[3] = breg[qg];
                acc[mt][qg] = v;
            }
        __syncthreads();   // gather (and prev-step h) visible to all waves

#define CHUNK(KC)                                                              \
        {                                                                      \
            _Pragma("unroll")                                                  \
            for (int mt = 0; mt < 4; ++mt) {                                   \
                short8v af = *(const short8v*)&Al[(mt * 16 + c) * 200 + (KC) * 32 + q * 8]; \
                _Pragma("unroll")                                              \
                for (int qg = 0; qg < 4; ++qg)                                 \
                    acc[mt][qg] = __builtin_amdgcn_mfma_f32_16x16x32_bf16(     \
                        af, Bfr[KC][qg], acc[mt][qg], 0, 0, 0);                \
            }                                                                  \
        }
        if (step == 0) {
            CHUNK(0) CHUNK(1)
        } else {
            CHUNK(0) CHUNK(1) CHUNK(2) CHUNK(3) CHUNK(4) CHUNK(5)
        }
#undef CHUNK
        __syncthreads();   // all A reads done before h-writeback / next gather

        // ---- activation: cell (mt,r): path mt*16+q*4+r, hidden 16w+c
#pragma unroll
        for (int mt = 0; mt < 4; ++mt) {
#pragma unroll
            for (int r = 0; r < 4; ++r) {
                float gi = acc[mt][0][r], gf = acc[mt][1][r];
                float gg = acc[mt][2][r], go = acc[mt][3][r];
                float ea = __expf(-gf), eb = __expf(-gi);
                float ed = __expf(-2.f * gg), eo = __expf(-go);
                float pa = 1.f + ea, pb = 1.f + eb, pd = 1.f + ed;
                float cn = (creg[mt * 4 + r] * pb * pd + (1.f - ed) * pa) *
                           __builtin_amdgcn_rcpf(pa * pb * pd);
                creg[mt * 4 + r] = cn;
                float et = __expf(-2.f * cn);
                float hn = (1.f - et) *
                           __builtin_amdgcn_rcpf((1.f + eo) * (1.f + et));
                if (step < L - 1) {
                    Al[(mt * 16 + q * 4 + r) * 200 + 128 + 16 * w + c] = bf16r(hn);
                } else {
                    long pr = (long)blockIdx.x * 64 + mt * 16 + q * 4 + r;
                    if (pr < P) {
                        int node = paths[pr * L + (L - 1)];
                        atomicAdd(hsum + (size_t)node * HD + 16 * w + c, hn);
                    }
                }
            }
        }
    }
}

// ---------------------------------------------------------------------------
// Per-column sum / sumsq over rows (for BN stats)
// ---------------------------------------------------------------------------
__global__ void col_stats(const float* __restrict__ X, int nrows, float* __restrict__ out) {
    int col = threadIdx.x & 63, rg = threadIdx.x >> 6;
    float s = 0.f, q = 0.f;
    long stride = (long)gridDim.x * 4;
    for (long r = (long)blockIdx.x * 4 + rg; r < nrows; r += stride) {
        float v = X[r * 64 + col];
        s += v;
        q += v * v;
    }
    __shared__ float red[2][256];
    red[0][threadIdx.x] = s;
    red[1][threadIdx.x] = q;
    __syncthreads();
    if (threadIdx.x < 64) {
        int c = threadIdx.x;
        float ss = red[0][c] + red[0][c + 64] + red[0][c + 128] + red[0][c + 192];
        float qq = red[1][c] + red[1][c + 64] + red[1][c + 128] + red[1][c + 192];
        atomicAdd(out + c, ss);
        atomicAdd(out + 64 + c, qq);
    }
}

// per-thread BN affine from raw stats (no separate finalize launch)
__device__ __forceinline__ void bn_affine(const float* stats, const float* g,
                                          const float* b, int col, int nrows,
                                          float& a, float& c) {
    float inv = 1.0f / (float)nrows;
    float mean = stats[col] * inv;
    float var = stats[64 + col] * inv - mean * mean;
    a = g[col] * rsqrtf(var + 1e-5f);
    c = b[col] - mean * a;
}

// ---------------------------------------------------------------------------
// Y[n][j] = sum_k inAct(X[n][k]*a[k]+c[k]) * W[k][j] + bias[j]
// BN affine computed in-kernel from raw stats; optional fused col-stats of Y.
// ---------------------------------------------------------------------------
template <bool INRELU, bool STATS>
__global__ __launch_bounds__(256)
void gemm64(const float* __restrict__ X, const float* __restrict__ stats_in,
            const float* __restrict__ bn_gm, const float* __restrict__ bn_bt,
            const float* __restrict__ W, const float* __restrict__ bias,
            float* __restrict__ Y, float* stats, int nrows) {
    __shared__ float Xs[64 * 64];
    __shared__ float red[2][256];
    const int t = threadIdx.x;
    const int col = t & 63, rg = t >> 6;
    const long r0 = (long)blockIdx.x * 64;

    float a = 1.f, c = 0.f;
    if (stats_in) bn_affine(stats_in, bn_gm, bn_bt, col, nrows, a, c);

    for (int i = 0; i < 16; ++i) {
        int rl = rg * 16 + i;
        long r = r0 + rl;
        float v = (r < nrows) ? X[r * 64 + col] : 0.f;
        v = v * a + c;
        if (INRELU) v = fmaxf(v, 0.f);
        Xs[rl * 64 + col] = v;
    }
    __syncthreads();

    float wreg[64];
#pragma unroll
    for (int k = 0; k < 64; ++k) wreg[k] = W[k * 64 + col];
    float bs = bias[col];
    float ssum = 0.f, ssq = 0.f;

    for (int i = 0; i < 16; ++i) {
        int rl = rg * 16 + i;
        long r = r0 + rl;
        const float4* xs4 = (const float4*)(Xs + rl * 64);
        float acc = bs;
#pragma unroll
        for (int k4 = 0; k4 < 16; ++k4) {
            float4 xv = xs4[k4];
            acc += xv.x * wreg[4 * k4] + xv.y * wreg[4 * k4 + 1] +
                   xv.z * wreg[4 * k4 + 2] + xv.w * wreg[4 * k4 + 3];
        }
        if (r < nrows) {
            Y[r * 64 + col] = acc;
            ssum += acc;
            ssq += acc * acc;
        }
    }
    if (STATS) {
        red[0][t] = ssum;
        red[1][t] = ssq;
        __syncthreads();
        if (t < 64) {
            float s = red[0][t] + red[0][t + 64] + red[0][t + 128] + red[0][t + 192];
            float qq = red[1][t] + red[1][t + 64] + red[1][t + 128] + red[1][t + 192];
            atomicAdd(stats + t, s);
            atomicAdd(stats + 64 + t, qq);
        }
    }
}

// conv1 epilogue: W1 = relu(BN(W1)); Winb = bf16(0.75*W0 - 0.25*W1)
__global__ void bn_apply1(float* __restrict__ W1, const float* __restrict__ stats,
                          const float* __restrict__ g, const float* __restrict__ b,
                          const float* __restrict__ W0, unsigned short* __restrict__ Winb,
                          long n) {
    long gid = (long)blockIdx.x * 256 + threadIdx.x;
    if (gid >= n * 64) return;
    int col = (int)(gid & 63);
    float a, c;
    bn_affine(stats, g, b, col, (int)n, a, c);
    float v = fmaxf(W1[gid] * a + c, 0.f);
    W1[gid] = v;
    Winb[gid] = bf16r(0.75f * W0[gid] - 0.25f * v);
}

// conv2 epilogue fused with attention dots:
// W2 = relu(BN(W2)); atts[h] += sum W0*W1; atts[64+h] += sum W0*W2
__global__ void bn_apply_att(float* __restrict__ W2, const float* __restrict__ stats,
                             const float* __restrict__ g, const float* __restrict__ b,
                             const float* __restrict__ W0, const float* __restrict__ W1,
                             float* __restrict__ atts, int n) {
    int col = threadIdx.x & 63, rg = threadIdx.x >> 6;
    float a, c;
    bn_affine(stats, g, b, col, n, a, c);
    float s1 = 0.f, s2 = 0.f;
    long stride = (long)gridDim.x * 4;
    for (long r = (long)blockIdx.x * 4 + rg; r < n; r += stride) {
        long gid = r * 64 + col;
        float v = fmaxf(W2[gid] * a + c, 0.f);
        W2[gid] = v;
        float q0 = W0[gid];
        s1 += q0 * W1[gid];
        s2 += q0 * v;
    }
    __shared__ float red[2][256];
    red[0][threadIdx.x] = s1;
    red[1][threadIdx.x] = s2;
    __syncthreads();
    if (threadIdx.x < 64) {
        int cc = threadIdx.x;
        float a1 = red[0][cc] + red[0][cc + 64] + red[0][cc + 128] + red[0][cc + 192];
        float a2 = red[1][cc] + red[1][cc + 64] + red[1][cc + 128] + red[1][cc + 192];
        atomicAdd(atts + cc, a1);
        atomicAdd(atts + 64 + cc, a2);
    }
}

// single wave: normalize scores, dot w_att, softmax over the 2 -> watt[0..1]
__global__ void att_softmax(const float* __restrict__ atts, const float* __restrict__ w_att,
                            const float* __restrict__ b_att, float* __restrict__ watt) {
    int h = threadIdx.x;  // 0..63
    float z[2];
    for (int k = 0; k < 2; ++k) {
        float s = atts[64 * k + h];
        float mn = s, mx = s;
        for (int off = 32; off > 0; off >>= 1) {
            mn = fminf(mn, __shfl_down(mn, off));
            mx = fmaxf(mx, __shfl_down(mx, off));
        }
        mn = __shfl(mn, 0);
        mx = __shfl(mx, 0);
        float sn = (s - mn) / (mx - mn + 1e-6f);
        float d = sn * w_att[h];
        for (int off = 32; off > 0; off >>= 1) d += __shfl_down(d, off);
        z[k] = __shfl(d, 0) + b_att[0];
    }
    if (h == 0) {
        float m = fmaxf(z[0], z[1]);
        float e0 = expf(z[0] - m), e1 = expf(z[1] - m);
        float inv = 1.0f / (e0 + e1);
        watt[0] = e0 * inv;
        watt[1] = e1 * inv;
    }
}

// rep = W0 + w1*W1 + w2*W2, scatter-add into pooled[batch[n]]
__global__ void pool_rep(const float* __restrict__ W0, const float* __restrict__ W1,
                         const float* __restrict__ W2, const float* __restrict__ watt,
                         const int* __restrict__ batch, float* __restrict__ pooled, int n) {
    long gid = (long)blockIdx.x * 256 + threadIdx.x;
    if (gid >= (long)n * 64) return;
    long r = gid >> 6;
    int col = (int)(gid & 63);
    float w1 = watt[0], w2 = watt[1];
    float rep = W0[gid] + w1 * W1[gid] + w2 * W2[gid];
    atomicAdd(pooled + (size_t)batch[r] * 64 + col, rep);
}

// out[g][j] = sum_k relu(X[g][k]) * W[k][j] + b[j]   (W is 64 x 10)
__global__ void lin2_kernel(const float* __restrict__ X, const float* __restrict__ W,
                            const float* __restrict__ b, float* __restrict__ out, int g_count) {
    int gid = blockIdx.x * 256 + threadIdx.x;
    if (gid >= g_count * NCLS) return;
    int g = gid / NCLS, j = gid - g * NCLS;
    float acc = b[j];
    const float* xr = X + (size_t)g * 64;
    for (int k = 0; k < 64; ++k) acc += fmaxf(xr[k], 0.f) * W[k * NCLS + j];
    out[gid] = acc;
}

// ---------------------------------------------------------------------------
extern "C" void kernel_launch(void* const* d_in, const int* in_sizes, int n_in,
                              void* d_out, int out_size, void* d_ws, size_t ws_size,
                              hipStream_t stream) {
    const float* x         = (const float*)d_in[0];
    const float* edge_attr = (const float*)d_in[1];
    const int*   paths2    = (const int*)d_in[2];
    const int*   ei2       = (const int*)d_in[3];
    const int*   paths3    = (const int*)d_in[4];
    const int*   ei3       = (const int*)d_in[5];
    const int*   batch     = (const int*)d_in[6];
    const float* w_feat    = (const float*)d_in[7];
    const float* b_feat    = (const float*)d_in[8];
    const float* w_bond    = (const float*)d_in[9];
    const float* b_bond    = (const float*)d_in[10];
    const float* w_ih      = (const float*)d_in[11];
    const float* w_hh      = (const float*)d_in[12];
    const float* b_ih      = (const float*)d_in[13];
    const float* b_hh      = (const float*)d_in[14];
    const float* bn_g      = (const float*)d_in[15];
    const float* bn_b      = (const float*)d_in[16];
    const float* mlp_w1    = (const float*)d_in[17];
    const float* mlp_b1    = (const float*)d_in[18];
    const float* bn1_g     = (const float*)d_in[19];
    const float* bn1_b     = (const float*)d_in[20];
    const float* mlp_w2    = (const float*)d_in[21];
    const float* mlp_b2    = (const float*)d_in[22];
    const float* bn2_g     = (const float*)d_in[23];
    const float* bn2_b     = (const float*)d_in[24];
    const float* w_att     = (const float*)d_in[25];
    const float* b_att     = (const float*)d_in[26];
    const float* w_l1      = (const float*)d_in[27];
    const float* b_l1      = (const float*)d_in[28];
    const float* w_l2      = (const float*)d_in[29];
    const float* b_l2      = (const float*)d_in[30];

    const size_t N64 = (size_t)NNODES * 64;
    float* ws = (float*)d_ws;
    float* W0     = ws;                               // N*64 f32
    float* W1     = W0 + N64;                         // N*64 f32
    float* W2     = W1 + N64;                         // N*64 f32
    float* Wtmp   = W2 + N64;                         // N*64 f32
    float* hsum   = Wtmp + N64;                       // N*64 f32
    unsigned short* W0b  = (unsigned short*)(hsum + N64);   // N*64 bf16
    unsigned short* Winb = W0b + N64;                       // N*64 bf16
    unsigned short* eab  = Winb + N64;                      // E*64 bf16
    unsigned short* Bp   = eab + (size_t)NEDGES * 64;       // 6*16*64*8 bf16 frag blobs
    float* bsum   = (float*)(Bp + 6 * 16 * 64 * 8);   // 256
    float* st     = bsum + 256;                       // 6*128
    float* atts   = st + 6 * 128;                     // 128
    float* watt   = atts + 128;                       // 64 (2 used)
    float* pooled = watt + 64;                        // G*64
    float* lin1   = pooled + (size_t)NG * 64;         // G*64

    // zero: stats region (st..watt inclusive), pooled, hsum
    hipMemsetAsync(st, 0, (6 * 128 + 128 + 64) * sizeof(float), stream);
    hipMemsetAsync(pooled, 0, (size_t)NG * 64 * sizeof(float), stream);
    hipMemsetAsync(hsum, 0, N64 * sizeof(float), stream);

    prep_bias<<<1, 256, 0, stream>>>(b_ih, b_hh, bsum);
    prep_bp<<<192, 256, 0, stream>>>(w_ih, w_hh, Bp);
    encode_both<<<(NNODES * 64 + 255) / 256, 256, 0, stream>>>(x, w_feat, b_feat, W0, W0b, NNODES, NFEAT);
    encode_bf<<<(NEDGES * 64 + 255) / 256, 256, 0, stream>>>(edge_attr, w_bond, b_bond, eab, NEDGES, EFEAT);

    // ---------------- conv 1 (L=2) ----------------
    conv_mfma<2><<<(NP2 + 63) / 64, 256, 0, stream>>>(W0b, eab, paths2, ei2, Bp, bsum, hsum, NP2);

    col_stats<<<256, 256, 0, stream>>>(hsum, NNODES, st + 0);
    gemm64<false, true><<<(NNODES + 63) / 64, 256, 0, stream>>>(hsum, st + 0, bn_g + 0, bn_b + 0, mlp_w1, mlp_b1, Wtmp, st + 128, NNODES);
    gemm64<true, true><<<(NNODES + 63) / 64, 256, 0, stream>>>(Wtmp, st + 128, bn1_g + 0, bn1_b + 0, mlp_w2, mlp_b2, W1, st + 256, NNODES);
    bn_apply1<<<(NNODES * 64 + 255) / 256, 256, 0, stream>>>(W1, st + 256, bn2_g + 0, bn2_b + 0, W0, Winb, NNODES);

    // ---------------- conv 2 (L=3) ----------------
    hipMemsetAsync(hsum, 0, N64 * sizeof(float), stream);
    conv_mfma<3><<<(NP3 + 63) / 64, 256, 0, stream>>>(Winb, eab, paths3, ei3, Bp, bsum, hsum, NP3);

    col_stats<<<256, 256, 0, stream>>>(hsum, NNODES, st + 384);
    gemm64<false, true><<<(NNODES + 63) / 64, 256, 0, stream>>>(hsum, st + 384, bn_g + 64, bn_b + 64, mlp_w1 + 4096, mlp_b1 + 64, Wtmp, st + 512, NNODES);
    gemm64<true, true><<<(NNODES + 63) / 64, 256, 0, stream>>>(Wtmp, st + 512, bn1_g + 64, bn1_b + 64, mlp_w2 + 4096, mlp_b2 + 64, W2, st + 640, NNODES);
    bn_apply_att<<<256, 256, 0, stream>>>(W2, st + 640, bn2_g + 64, bn2_b + 64, W0, W1, atts, NNODES);

    // ---------------- attention + pooling + head ----------------
    att_softmax<<<1, 64, 0, stream>>>(atts, w_att, b_att, watt);
    pool_rep<<<(NNODES * 64 + 255) / 256, 256, 0, stream>>>(W0, W1, W2, watt, batch, pooled, NNODES);
    gemm64<false, false><<<NG / 64, 256, 0, stream>>>(pooled, nullptr, nullptr, nullptr, w_l1, b_l1, lin1, nullptr, NG);
    lin2_kernel<<<(NG * NCLS + 255) / 256, 256, 0, stream>>>(lin1, w_l2, b_l2, (float*)d_out, NG);
}

// Round 6
// 917.897 us; speedup vs baseline: 1.3287x; 1.0736x over previous
//
#include <hip/hip_runtime.h>
#include <math.h>

#define NNODES 100000
#define NEDGES 200000
#define HD 64
#define NP2 250000
#define NP3 500000
#define NG 2048
#define NCLS 10
#define NFEAT 18
#define EFEAT 18

typedef short short8v __attribute__((ext_vector_type(8)));
typedef float f32x4 __attribute__((ext_vector_type(4)));

__device__ __forceinline__ unsigned short bf16r(float a) {
    unsigned u = __builtin_bit_cast(unsigned, a);
    return (unsigned short)((u + 0x7FFFu + ((u >> 16) & 1u)) >> 16);
}

// ---------------------------------------------------------------------------
// bsum[j] = b_ih[j] + b_hh[j]
// ---------------------------------------------------------------------------
__global__ void prep_bias(const float* __restrict__ b_ih, const float* __restrict__ b_hh,
                          float* __restrict__ bsum) {
    int j = threadIdx.x;
    bsum[j] = b_ih[j] + b_hh[j];
}

// ---------------------------------------------------------------------------
// Bp: bf16 B image as MFMA fragment blobs (same layout as R5).
// Bp[((kc*16 + nt)*64 + l)*8 + j] = bf16(B[k][n]),
//   k = kc*32 + (l>>4)*8 + j,  nt = jh*4 + qg,  n = qg*64 + 16*jh + (l&15).
// ---------------------------------------------------------------------------
__global__ void prep_bp(const float* __restrict__ w_ih, const float* __restrict__ w_hh,
                        unsigned short* __restrict__ Bp) {
    int gid = blockIdx.x * 256 + threadIdx.x;
    if (gid >= 6 * 16 * 64 * 8) return;
    int kc = gid >> 13;
    int rem = gid & 8191;
    int nt = rem >> 9;
    int rem2 = rem & 511;
    int l = rem2 >> 3, j = rem2 & 7;
    int c = l & 15, q = l >> 4;
    int jh = nt >> 2, qg = nt & 3;
    int k = kc * 32 + q * 8 + j;
    int n = qg * 64 + 16 * jh + c;
    float f = (k < 128) ? w_ih[n * 128 + k] : w_hh[n * 64 + (k - 128)];
    Bp[gid] = bf16r(f);
}

// ---------------------------------------------------------------------------
// Combined feature encoder: rows < NNODES -> node enc (W0 f32 + W0b bf16),
// rows >= NNODES -> edge enc (eab bf16).
// ---------------------------------------------------------------------------
__global__ void encode_all(const float* __restrict__ X, const float* __restrict__ Wf,
                           const float* __restrict__ bf,
                           const float* __restrict__ Ea, const float* __restrict__ Wb,
                           const float* __restrict__ bb,
                           float* __restrict__ W0, unsigned short* __restrict__ W0b,
                           unsigned short* __restrict__ eab) {
    long gid = (long)blockIdx.x * 256 + threadIdx.x;
    if (gid >= (long)(NNODES + NEDGES) * 64) return;
    long r = gid >> 6;
    int col = (int)(gid & 63);
    if (r < NNODES) {
        float acc = bf[col];
        const float* xr = X + r * NFEAT;
        for (int k = 0; k < NFEAT; ++k) acc += xr[k] * Wf[k * 64 + col];
        W0[gid] = acc;
        W0b[gid] = bf16r(acc);
    } else {
        long r2 = r - NNODES;
        float acc = bb[col];
        const float* xr = Ea + r2 * EFEAT;
        for (int k = 0; k < EFEAT; ++k) acc += xr[k] * Wb[k * 64 + col];
        eab[r2 * 64 + col] = bf16r(acc);
    }
}

// ---------------------------------------------------------------------------
// MFMA LSTM path conv, register-resident B + next-step gather prefetch.
// Block = 256 threads (4 waves) x 64 paths.  Al (LDS, bf16): [p=64][k],
// stride 200 shorts; k 0..63 node, 64..127 edge, 128..191 h(prev step).
// Wave w: acc[mt][qg] over hidden [16w,16w+16).  Per step: 2 barriers,
// 24 ds_read_b128, 96 MFMA.  Next step's node/edge rows are loaded into
// registers right after the pre-MFMA barrier (latency hidden behind
// MFMA + activation) and written to LDS at the next loop head.
// ---------------------------------------------------------------------------
template <int L>
__global__ __launch_bounds__(256, 2)
void conv_mfma(const unsigned short* __restrict__ xb, const unsigned short* __restrict__ eab,
               const int* __restrict__ paths, const int* __restrict__ ei,
               const unsigned short* __restrict__ Bp, const float* __restrict__ bsum,
               float* __restrict__ hsum, int P) {
    __shared__ unsigned short Al[64 * 200];

    const int t = threadIdx.x;
    const int w = t >> 6, lane = t & 63;
    const int c = lane & 15, q = lane >> 4;
    const int pl = t >> 2, gq = t & 3;          // gather: path-local, row quarter
    const long pg = (long)blockIdx.x * 64 + pl;
    const int pc = (pg < P) ? (int)pg : P - 1;

    // ---- B fragments: register-resident for the whole kernel
    short8v Bfr[6][4];
#pragma unroll
    for (int kc = 0; kc < 6; ++kc)
#pragma unroll
        for (int qg = 0; qg < 4; ++qg)
            Bfr[kc][qg] = *(const short8v*)&Bp[(((kc * 16) + (w * 4 + qg)) * 64 + lane) * 8];

    float breg[4];
#pragma unroll
    for (int qg = 0; qg < 4; ++qg) breg[qg] = bsum[qg * 64 + 16 * w + c];

    float creg[16];
#pragma unroll
    for (int i = 0; i < 16; ++i) creg[i] = 0.f;

    f32x4 acc[4][4];

    // ---- prefetch step-0 node row
    uint4 nu0, nu1, ev0, ev1;
    {
        int node = paths[pc * L + 0];
        const uint4* s4 = (const uint4*)(xb + (size_t)node * HD);
        nu0 = s4[2 * gq]; nu1 = s4[2 * gq + 1];
    }

    for (int step = 0; step < L; ++step) {
        // ---- write prefetched rows -> Al (node 0..63, edge 64..127)
        *(uint4*)&Al[pl * 200 + gq * 16] = nu0;
        *(uint4*)&Al[pl * 200 + gq * 16 + 8] = nu1;
        if (step > 0) {
            *(uint4*)&Al[pl * 200 + 64 + gq * 16] = ev0;
            *(uint4*)&Al[pl * 200 + 64 + gq * 16 + 8] = ev1;
        }
        // ---- init accumulators with bias
#pragma unroll
        for (int mt = 0; mt < 4; ++mt)
#pragma unroll
            for (int qg = 0; qg < 4; ++qg) {
                f32x4 v; v[0] = breg[qg]; v[1] = breg[qg]; v[2] = breg[qg]; v[3] = breg[qg];
                acc[mt][qg] = v;
            }
        __syncthreads();   // gather (and prev-step h) visible to all waves

        // ---- issue next step's global loads now; consumed next iteration
        if (step + 1 < L) {
            int node = paths[pc * L + step + 1];
            const uint4* s4 = (const uint4*)(xb + (size_t)node * HD);
            nu0 = s4[2 * gq]; nu1 = s4[2 * gq + 1];
            int e = ei[pc * (L - 1) + step];
            const uint4* e4 = (const uint4*)(eab + (size_t)e * HD);
            ev0 = e4[2 * gq]; ev1 = e4[2 * gq + 1];
        }

#define CHUNK(KC)                                                              \
        {                                                                      \
            _Pragma("unroll")                                                  \
            for (int mt = 0; mt < 4; ++mt) {                                   \
                short8v af = *(const short8v*)&Al[(mt * 16 + c) * 200 + (KC) * 32 + q * 8]; \
                _Pragma("unroll")                                              \
                for (int qg = 0; qg < 4; ++qg)                                 \
                    acc[mt][qg] = __builtin_amdgcn_mfma_f32_16x16x32_bf16(     \
                        af, Bfr[KC][qg], acc[mt][qg], 0, 0, 0);                \
            }                                                                  \
        }
        if (step == 0) {
            CHUNK(0) CHUNK(1)
        } else {
            CHUNK(0) CHUNK(1) CHUNK(2) CHUNK(3) CHUNK(4) CHUNK(5)
        }
#undef CHUNK
        __syncthreads();   // all A reads done before h-writeback / next gather

        // ---- activation: cell (mt,r): path mt*16+q*4+r, hidden 16w+c
#pragma unroll
        for (int mt = 0; mt < 4; ++mt) {
#pragma unroll
            for (int r = 0; r < 4; ++r) {
                float gi = acc[mt][0][r], gf = acc[mt][1][r];
                float gg = acc[mt][2][r], go = acc[mt][3][r];
                float ea = __expf(-gf), eb = __expf(-gi);
                float ed = __expf(-2.f * gg), eo = __expf(-go);
                float pa = 1.f + ea, pb = 1.f + eb, pd = 1.f + ed;
                float cn = (creg[mt * 4 + r] * pb * pd + (1.f - ed) * pa) *
                           __builtin_amdgcn_rcpf(pa * pb * pd);
                creg[mt * 4 + r] = cn;
                float et = __expf(-2.f * cn);
                float hn = (1.f - et) *
                           __builtin_amdgcn_rcpf((1.f + eo) * (1.f + et));
                if (step < L - 1) {
                    Al[(mt * 16 + q * 4 + r) * 200 + 128 + 16 * w + c] = bf16r(hn);
                } else {
                    long pr = (long)blockIdx.x * 64 + mt * 16 + q * 4 + r;
                    if (pr < P) {
                        int node = paths[pr * L + (L - 1)];
                        atomicAdd(hsum + (size_t)node * HD + 16 * w + c, hn);
                    }
                }
            }
        }
    }
}

// ---------------------------------------------------------------------------
// Per-column sum / sumsq over rows (for BN stats)
// ---------------------------------------------------------------------------
__global__ void col_stats(const float* __restrict__ X, int nrows, float* __restrict__ out) {
    int col = threadIdx.x & 63, rg = threadIdx.x >> 6;
    float s = 0.f, q = 0.f;
    long stride = (long)gridDim.x * 4;
    for (long r = (long)blockIdx.x * 4 + rg; r < nrows; r += stride) {
        float v = X[r * 64 + col];
        s += v;
        q += v * v;
    }
    __shared__ float red[2][256];
    red[0][threadIdx.x] = s;
    red[1][threadIdx.x] = q;
    __syncthreads();
    if (threadIdx.x < 64) {
        int c = threadIdx.x;
        float ss = red[0][c] + red[0][c + 64] + red[0][c + 128] + red[0][c + 192];
        float qq = red[1][c] + red[1][c + 64] + red[1][c + 128] + red[1][c + 192];
        atomicAdd(out + c, ss);
        atomicAdd(out + 64 + c, qq);
    }
}

// per-thread BN affine from raw stats
__device__ __forceinline__ void bn_affine(const float* stats, const float* g,
                                          const float* b, int col, int nrows,
                                          float& a, float& c) {
    float inv = 1.0f / (float)nrows;
    float mean = stats[col] * inv;
    float var = stats[64 + col] * inv - mean * mean;
    a = g[col] * rsqrtf(var + 1e-5f);
    c = b[col] - mean * a;
}

// ---------------------------------------------------------------------------
// Y[n][j] = sum_k inAct(X[n][k]*a[k]+c[k]) * W[k][j] + bias[j]
// BN affine computed in-kernel from raw stats; optional fused col-stats of Y.
// ---------------------------------------------------------------------------
template <bool INRELU, bool STATS>
__global__ __launch_bounds__(256)
void gemm64(const float* __restrict__ X, const float* __restrict__ stats_in,
            const float* __restrict__ bn_gm, const float* __restrict__ bn_bt,
            const float* __restrict__ W, const float* __restrict__ bias,
            float* __restrict__ Y, float* stats, int nrows) {
    __shared__ float Xs[64 * 64];
    __shared__ float red[2][256];
    const int t = threadIdx.x;
    const int col = t & 63, rg = t >> 6;
    const long r0 = (long)blockIdx.x * 64;

    float a = 1.f, c = 0.f;
    if (stats_in) bn_affine(stats_in, bn_gm, bn_bt, col, nrows, a, c);

    for (int i = 0; i < 16; ++i) {
        int rl = rg * 16 + i;
        long r = r0 + rl;
        float v = (r < nrows) ? X[r * 64 + col] : 0.f;
        v = v * a + c;
        if (INRELU) v = fmaxf(v, 0.f);
        Xs[rl * 64 + col] = v;
    }
    __syncthreads();

    float wreg[64];
#pragma unroll
    for (int k = 0; k < 64; ++k) wreg[k] = W[k * 64 + col];
    float bs = bias[col];
    float ssum = 0.f, ssq = 0.f;

    for (int i = 0; i < 16; ++i) {
        int rl = rg * 16 + i;
        long r = r0 + rl;
        const float4* xs4 = (const float4*)(Xs + rl * 64);
        float acc = bs;
#pragma unroll
        for (int k4 = 0; k4 < 16; ++k4) {
            float4 xv = xs4[k4];
            acc += xv.x * wreg[4 * k4] + xv.y * wreg[4 * k4 + 1] +
                   xv.z * wreg[4 * k4 + 2] + xv.w * wreg[4 * k4 + 3];
        }
        if (r < nrows) {
            Y[r * 64 + col] = acc;
            ssum += acc;
            ssq += acc * acc;
        }
    }
    if (STATS) {
        red[0][t] = ssum;
        red[1][t] = ssq;
        __syncthreads();
        if (t < 64) {
            float s = red[0][t] + red[0][t + 64] + red[0][t + 128] + red[0][t + 192];
            float qq = red[1][t] + red[1][t + 64] + red[1][t + 128] + red[1][t + 192];
            atomicAdd(stats + t, s);
            atomicAdd(stats + 64 + t, qq);
        }
    }
}

// conv1 epilogue: W1 = relu(BN(W1)); Winb = bf16(0.75*W0 - 0.25*W1)
__global__ void bn_apply1(float* __restrict__ W1, const float* __restrict__ stats,
                          const float* __restrict__ g, const float* __restrict__ b,
                          const float* __restrict__ W0, unsigned short* __restrict__ Winb,
                          long n) {
    long gid = (long)blockIdx.x * 256 + threadIdx.x;
    if (gid >= n * 64) return;
    int col = (int)(gid & 63);
    float a, c;
    bn_affine(stats, g, b, col, (int)n, a, c);
    float v = fmaxf(W1[gid] * a + c, 0.f);
    W1[gid] = v;
    Winb[gid] = bf16r(0.75f * W0[gid] - 0.25f * v);
}

// conv2 epilogue fused with attention dots:
// W2 = relu(BN(W2)); atts[h] += sum W0*W1; atts[64+h] += sum W0*W2
__global__ void bn_apply_att(float* __restrict__ W2, const float* __restrict__ stats,
                             const float* __restrict__ g, const float* __restrict__ b,
                             const float* __restrict__ W0, const float* __restrict__ W1,
                             float* __restrict__ atts, int n) {
    int col = threadIdx.x & 63, rg = threadIdx.x >> 6;
    float a, c;
    bn_affine(stats, g, b, col, n, a, c);
    float s1 = 0.f, s2 = 0.f;
    long stride = (long)gridDim.x * 4;
    for (long r = (long)blockIdx.x * 4 + rg; r < n; r += stride) {
        long gid = r * 64 + col;
        float v = fmaxf(W2[gid] * a + c, 0.f);
        W2[gid] = v;
        float q0 = W0[gid];
        s1 += q0 * W1[gid];
        s2 += q0 * v;
    }
    __shared__ float red[2][256];
    red[0][threadIdx.x] = s1;
    red[1][threadIdx.x] = s2;
    __syncthreads();
    if (threadIdx.x < 64) {
        int cc = threadIdx.x;
        float a1 = red[0][cc] + red[0][cc + 64] + red[0][cc + 128] + red[0][cc + 192];
        float a2 = red[1][cc] + red[1][cc + 64] + red[1][cc + 128] + red[1][cc + 192];
        atomicAdd(atts + cc, a1);
        atomicAdd(atts + 64 + cc, a2);
    }
}

// single wave: normalize scores, dot w_att, softmax over the 2 -> watt[0..1]
__global__ void att_softmax(const float* __restrict__ atts, const float* __restrict__ w_att,
                            const float* __restrict__ b_att, float* __restrict__ watt) {
    int h = threadIdx.x;  // 0..63
    float z[2];
    for (int k = 0; k < 2; ++k) {
        float s = atts[64 * k + h];
        float mn = s, mx = s;
        for (int off = 32; off > 0; off >>= 1) {
            mn = fminf(mn, __shfl_down(mn, off));
            mx = fmaxf(mx, __shfl_down(mx, off));
        }
        mn = __shfl(mn, 0);
        mx = __shfl(mx, 0);
        float sn = (s - mn) / (mx - mn + 1e-6f);
        float d = sn * w_att[h];
        for (int off = 32; off > 0; off >>= 1) d += __shfl_down(d, off);
        z[k] = __shfl(d, 0) + b_att[0];
    }
    if (h == 0) {
        float m = fmaxf(z[0], z[1]);
        float e0 = expf(z[0] - m), e1 = expf(z[1] - m);
        float inv = 1.0f / (e0 + e1);
        watt[0] = e0 * inv;
        watt[1] = e1 * inv;
    }
}

// rep = W0 + w1*W1 + w2*W2, segmented scatter-add into pooled[batch[n]].
// batch is sorted: accumulate per-thread runs, one atomic per run.
#define PROWS 128
__global__ void pool_rep(const float* __restrict__ W0, const float* __restrict__ W1,
                         const float* __restrict__ W2, const float* __restrict__ watt,
                         const int* __restrict__ batch, float* __restrict__ pooled, int n) {
    int col = threadIdx.x & 63, rg = threadIdx.x >> 6;
    long r0 = (long)blockIdx.x * PROWS;
    float w1 = watt[0], w2 = watt[1];
    float acc = 0.f;
    int curg = -1;
    for (int i = rg; i < PROWS; i += 4) {
        long r = r0 + i;
        if (r >= n) break;
        int g = batch[r];
        long gid = r * 64 + col;
        float rep = W0[gid] + w1 * W1[gid] + w2 * W2[gid];
        if (g != curg) {
            if (curg >= 0) atomicAdd(pooled + (size_t)curg * 64 + col, acc);
            curg = g;
            acc = 0.f;
        }
        acc += rep;
    }
    if (curg >= 0) atomicAdd(pooled + (size_t)curg * 64 + col, acc);
}

// fused head: lin1 = relu(relu(pooled) @ w_l1 + b_l1); out = lin1 @ w_l2 + b_l2
__global__ __launch_bounds__(256)
void head_kernel(const float* __restrict__ pooled, const float* __restrict__ w_l1,
                 const float* __restrict__ b_l1, const float* __restrict__ w_l2,
                 const float* __restrict__ b_l2, float* __restrict__ out) {
    __shared__ float Xs[64 * 64];
    __shared__ float Ys[64 * 65];
    const int t = threadIdx.x;
    const int col = t & 63, rg = t >> 6;
    const int r0 = blockIdx.x * 64;

    for (int i = 0; i < 16; ++i) {
        int rl = rg * 16 + i;
        Xs[rl * 64 + col] = fmaxf(pooled[(size_t)(r0 + rl) * 64 + col], 0.f);
    }
    __syncthreads();

    float wreg[64];
#pragma unroll
    for (int k = 0; k < 64; ++k) wreg[k] = w_l1[k * 64 + col];
    float bs = b_l1[col];

    for (int i = 0; i < 16; ++i) {
        int rl = rg * 16 + i;
        const float4* xs4 = (const float4*)(Xs + rl * 64);
        float acc = bs;
#pragma unroll
        for (int k4 = 0; k4 < 16; ++k4) {
            float4 xv = xs4[k4];
            acc += xv.x * wreg[4 * k4] + xv.y * wreg[4 * k4 + 1] +
                   xv.z * wreg[4 * k4 + 2] + xv.w * wreg[4 * k4 + 3];
        }
        Ys[rl * 65 + col] = fmaxf(acc, 0.f);
    }
    __syncthreads();

    for (int idx = t; idx < 64 * NCLS; idx += 256) {
        int row = idx / NCLS, j = idx - row * NCLS;
        float acc = b_l2[j];
#pragma unroll
        for (int k = 0; k < 64; ++k) acc += Ys[row * 65 + k] * w_l2[k * NCLS + j];
        out[(size_t)(r0 + row) * NCLS + j] = acc;
    }
}

// ---------------------------------------------------------------------------
extern "C" void kernel_launch(void* const* d_in, const int* in_sizes, int n_in,
                              void* d_out, int out_size, void* d_ws, size_t ws_size,
                              hipStream_t stream) {
    const float* x         = (const float*)d_in[0];
    const float* edge_attr = (const float*)d_in[1];
    const int*   paths2    = (const int*)d_in[2];
    const int*   ei2       = (const int*)d_in[3];
    const int*   paths3    = (const int*)d_in[4];
    const int*   ei3       = (const int*)d_in[5];
    const int*   batch     = (const int*)d_in[6];
    const float* w_feat    = (const float*)d_in[7];
    const float* b_feat    = (const float*)d_in[8];
    const float* w_bond    = (const float*)d_in[9];
    const float* b_bond    = (const float*)d_in[10];
    const float* w_ih      = (const float*)d_in[11];
    const float* w_hh      = (const float*)d_in[12];
    const float* b_ih      = (const float*)d_in[13];
    const float* b_hh      = (const float*)d_in[14];
    const float* bn_g      = (const float*)d_in[15];
    const float* bn_b      = (const float*)d_in[16];
    const float* mlp_w1    = (const float*)d_in[17];
    const float* mlp_b1    = (const float*)d_in[18];
    const float* bn1_g     = (const float*)d_in[19];
    const float* bn1_b     = (const float*)d_in[20];
    const float* mlp_w2    = (const float*)d_in[21];
    const float* mlp_b2    = (const float*)d_in[22];
    const float* bn2_g     = (const float*)d_in[23];
    const float* bn2_b     = (const float*)d_in[24];
    const float* w_att     = (const float*)d_in[25];
    const float* b_att     = (const float*)d_in[26];
    const float* w_l1      = (const float*)d_in[27];
    const float* b_l1      = (const float*)d_in[28];
    const float* w_l2      = (const float*)d_in[29];
    const float* b_l2      = (const float*)d_in[30];

    const size_t N64 = (size_t)NNODES * 64;
    float* ws = (float*)d_ws;
    float* W0     = ws;                               // N*64 f32
    float* W1     = W0 + N64;                         // N*64 f32
    float* W2     = W1 + N64;                         // N*64 f32
    float* Wtmp   = W2 + N64;                         // N*64 f32
    float* hsum1  = Wtmp + N64;                       // N*64 f32
    float* hsum2  = hsum1 + N64;                      // N*64 f32
    unsigned short* W0b  = (unsigned short*)(hsum2 + N64);  // N*64 bf16
    unsigned short* Winb = W0b + N64;                       // N*64 bf16
    unsigned short* eab  = Winb + N64;                      // E*64 bf16
    unsigned short* Bp   = eab + (size_t)NEDGES * 64;       // 6*16*64*8 bf16 frag blobs
    float* bsum   = (float*)(Bp + 6 * 16 * 64 * 8);   // 256
    float* st     = bsum + 256;                       // 6*128
    float* atts   = st + 6 * 128;                     // 128
    float* watt   = atts + 128;                       // 64 (2 used)
    float* pooled = watt + 64;                        // G*64

    // zero: stats region (st..watt), pooled, both hsum buffers (one call)
    hipMemsetAsync(st, 0, (6 * 128 + 128 + 64) * sizeof(float), stream);
    hipMemsetAsync(pooled, 0, (size_t)NG * 64 * sizeof(float), stream);
    hipMemsetAsync(hsum1, 0, 2 * N64 * sizeof(float), stream);

    prep_bias<<<1, 256, 0, stream>>>(b_ih, b_hh, bsum);
    prep_bp<<<192, 256, 0, stream>>>(w_ih, w_hh, Bp);
    encode_all<<<(int)(((size_t)(NNODES + NEDGES) * 64 + 255) / 256), 256, 0, stream>>>(
        x, w_feat, b_feat, edge_attr, w_bond, b_bond, W0, W0b, eab);

    // ---------------- conv 1 (L=2) ----------------
    conv_mfma<2><<<(NP2 + 63) / 64, 256, 0, stream>>>(W0b, eab, paths2, ei2, Bp, bsum, hsum1, NP2);

    col_stats<<<1024, 256, 0, stream>>>(hsum1, NNODES, st + 0);
    gemm64<false, true><<<(NNODES + 63) / 64, 256, 0, stream>>>(hsum1, st + 0, bn_g + 0, bn_b + 0, mlp_w1, mlp_b1, Wtmp, st + 128, NNODES);
    gemm64<true, true><<<(NNODES + 63) / 64, 256, 0, stream>>>(Wtmp, st + 128, bn1_g + 0, bn1_b + 0, mlp_w2, mlp_b2, W1, st + 256, NNODES);
    bn_apply1<<<(NNODES * 64 + 255) / 256, 256, 0, stream>>>(W1, st + 256, bn2_g + 0, bn2_b + 0, W0, Winb, NNODES);

    // ---------------- conv 2 (L=3) ----------------
    conv_mfma<3><<<(NP3 + 63) / 64, 256, 0, stream>>>(Winb, eab, paths3, ei3, Bp, bsum, hsum2, NP3);

    col_stats<<<1024, 256, 0, stream>>>(hsum2, NNODES, st + 384);
    gemm64<false, true><<<(NNODES + 63) / 64, 256, 0, stream>>>(hsum2, st + 384, bn_g + 64, bn_b + 64, mlp_w1 + 4096, mlp_b1 + 64, Wtmp, st + 512, NNODES);
    gemm64<true, true><<<(NNODES + 63) / 64, 256, 0, stream>>>(Wtmp, st + 512, bn1_g + 64, bn1_b + 64, mlp_w2 + 4096, mlp_b2 + 64, W2, st + 640, NNODES);
    bn_apply_att<<<1024, 256, 0, stream>>>(W2, st + 640, bn2_g + 64, bn2_b + 64, W0, W1, atts, NNODES);

    // ---------------- attention + pooling + head ----------------
    att_softmax<<<1, 64, 0, stream>>>(atts, w_att, b_att, watt);
    pool_rep<<<(NNODES + PROWS - 1) / PROWS, 256, 0, stream>>>(W0, W1, W2, watt, batch, pooled, NNODES);
    head_kernel<<<NG / 64, 256, 0, stream>>>(pooled, w_l1, b_l1, w_l2, b_l2, (float*)d_out);
}